// Round 4
// baseline (699.681 us; speedup 1.0000x reference)
//
#include <hip/hip_runtime.h>
#include <hip/hip_bf16.h>
#include <cstdint>
#include <cstddef>

// B=2, L=2048, D=1024, F=4096, E=8, K=2
#define B_ 2
#define L_ 2048
#define D_ 1024
#define F_ 4096
#define E_ 8
#define NTOK 4096
#define MAXROWS 9216   // sum over experts of pad128(n_e) <= 8192 + 8*127

typedef __hip_bfloat16 bf16;
typedef __attribute__((ext_vector_type(8))) short short8;
typedef __attribute__((ext_vector_type(4))) float floatx4;

typedef const __attribute__((address_space(1))) uint32_t* gptr_t;
typedef __attribute__((address_space(3))) uint32_t* lptr_t;

__device__ __forceinline__ void async_load16(const bf16* gp, bf16* lp) {
    __builtin_amdgcn_global_load_lds((gptr_t)(const void*)gp, (lptr_t)(void*)lp, 16, 0, 0);
}

__device__ __forceinline__ uint16_t bfbits(bf16 h) {
    union { bf16 b; uint16_t u; } v; v.b = h; return v.u;
}
__device__ __forceinline__ uint32_t pack2(float a, float b) {
    return (uint32_t)bfbits(__float2bfloat16(a)) | ((uint32_t)bfbits(__float2bfloat16(b)) << 16);
}

// ---------------- gating: 256 blocks x 256 thr, 16 tokens/block (4/wave) ----------------
__global__ __launch_bounds__(256) void gate_kernel(
    const float* __restrict__ x, const float* __restrict__ Wg,
    const float* __restrict__ bg, float* __restrict__ psum_pad,
    uint32_t* __restrict__ top_ids, float* __restrict__ top_w)
{
    __shared__ float psum_l[E_];
    int t = threadIdx.x;
    if (t < E_) psum_l[t] = 0.f;
    __syncthreads();

    int wave = t >> 6, lane = t & 63;
    for (int j = 0; j < 4; ++j) {
        int token = blockIdx.x * 16 + wave * 4 + j;
        const float* xr = x + (size_t)token * D_;

        float acc[E_];
#pragma unroll
        for (int e = 0; e < E_; ++e) acc[e] = 0.f;
        for (int i = 0; i < D_/64; ++i) {
            int d = lane + 64*i;
            float xv = xr[d];
            const float4* wr4 = (const float4*)(Wg + (size_t)d * E_);
            float4 wa = wr4[0], wb = wr4[1];
            acc[0] += xv * wa.x;  acc[1] += xv * wa.y;
            acc[2] += xv * wa.z;  acc[3] += xv * wa.w;
            acc[4] += xv * wb.x;  acc[5] += xv * wb.y;
            acc[6] += xv * wb.z;  acc[7] += xv * wb.w;
        }
#pragma unroll
        for (int off = 32; off >= 1; off >>= 1) {
#pragma unroll
            for (int e = 0; e < E_; ++e) acc[e] += __shfl_xor(acc[e], off, 64);
        }
        if (lane == 0) {
            float s[E_];
#pragma unroll
            for (int e = 0; e < E_; ++e) s[e] = acc[e] + bg[e];
            int i0 = 0;
#pragma unroll
            for (int e = 1; e < E_; ++e) if (s[e] > s[i0]) i0 = e;
            int i1 = -1;
#pragma unroll
            for (int e = 0; e < E_; ++e) {
                if (e == i0) continue;
                if (i1 < 0 || s[e] > s[i1]) i1 = e;
            }
            float e1 = expf(s[i1] - s[i0]);
            float w0 = 1.f / (1.f + e1);
            float w1 = e1 * w0;
            top_ids[token] = (uint32_t)i0 | ((uint32_t)i1 << 8);
            top_w[token]        = w0;
            top_w[NTOK + token] = w1;

            float mx = s[i0], p[E_], sum = 0.f;
#pragma unroll
            for (int e = 0; e < E_; ++e) { p[e] = expf(s[e] - mx); sum += p[e]; }
            float inv = 1.f / sum;
#pragma unroll
            for (int e = 0; e < E_; ++e) atomicAdd(&psum_l[e], p[e] * inv);
        }
    }
    __syncthreads();
    if (t < E_) atomicAdd(&psum_pad[t * 32], psum_l[t]);
}

// ---------------- deterministic per-expert compaction ----------------
__global__ __launch_bounds__(256) void compact_kernel(
    const uint32_t* __restrict__ top_ids, const float* __restrict__ top_w,
    int* __restrict__ cnt, int* __restrict__ tok_list, float* __restrict__ w_list)
{
    int e = blockIdx.x;
    int t = threadIdx.x, wave = t >> 6, lane = t & 63;
    __shared__ int wcnt[4];
    int base = 0;
    for (int r0 = 0; r0 < NTOK; r0 += 256) {
        int token = r0 + t;
        uint32_t ids = top_ids[token];
        int slot = -1;
        if ((int)(ids & 255u) == e) slot = 0;
        else if ((int)((ids >> 8) & 255u) == e) slot = 1;
        unsigned long long mask = __ballot(slot >= 0);
        int lpos = __popcll(mask & ((1ull << lane) - 1ull));
        if (lane == 0) wcnt[wave] = (int)__popcll(mask);
        __syncthreads();
        int woff = 0, tot = 0;
#pragma unroll
        for (int w2 = 0; w2 < 4; ++w2) { if (w2 < wave) woff += wcnt[w2]; tot += wcnt[w2]; }
        if (slot >= 0) {
            int pos = base + woff + lpos;
            tok_list[e*NTOK + pos] = token;
            w_list[e*NTOK + pos]   = top_w[slot*NTOK + token];
        }
        base += tot;
        __syncthreads();
    }
    if (t == 0) cnt[e] = base;
}

// ---------------- finalize: padded prefix offsets + loss ----------------
__global__ void finalize_gate_kernel(const int* __restrict__ cnt, const float* __restrict__ psum_pad,
                                     int* __restrict__ off, float* __restrict__ loss_out)
{
    int o = 0; float Ls = 0.f;
    for (int e = 0; e < E_; ++e) {
        off[e] = o;
        o += (cnt[e] + 127) & ~127;
        Ls += (float)cnt[e] * psum_pad[e * 32];
    }
    loss_out[0] = (float)E_ * Ls / ((float)NTOK * (float)NTOK);
}

// ---------------- weight transpose+convert, LDS-free register version ----------------
// [R][C] f32 -> [C][R] bf16 per expert. Each thread: 4x4 fp32 micro-tile,
// 4 coalesced float4 row loads, in-register transpose + packed bf16 convert,
// 4x 8B column stores (L2 assembles full 128B lines per output row).
__global__ __launch_bounds__(256) void transpose_bf16_kernel(
    const float* __restrict__ in, bf16* __restrict__ outp, int R, int C)
{
    int tilesR = R >> 6, tilesC = C >> 6;
    int per = tilesR * tilesC;
    int bx = blockIdx.x;
    int e  = bx / per; int r2 = bx % per;
    int tr = r2 / tilesC, tc = r2 % tilesC;
    int r0 = tr << 6, c0 = tc << 6;
    const float* ip = in  + (size_t)e * R * C;
    bf16*        op = outp + (size_t)e * R * C;

    int t = threadIdx.x;
    int c = (t & 15) * 4;   // col within tile
    int r = (t >> 4) * 4;   // row within tile

    const float* p0 = ip + (size_t)(r0 + r) * C + c0 + c;
    float4 v0 = *(const float4*)(p0);
    float4 v1 = *(const float4*)(p0 + C);
    float4 v2 = *(const float4*)(p0 + 2*C);
    float4 v3 = *(const float4*)(p0 + 3*C);

    uint2 o0, o1, o2, o3;
    o0.x = pack2(v0.x, v1.x);  o0.y = pack2(v2.x, v3.x);
    o1.x = pack2(v0.y, v1.y);  o1.y = pack2(v2.y, v3.y);
    o2.x = pack2(v0.z, v1.z);  o2.y = pack2(v2.z, v3.z);
    o3.x = pack2(v0.w, v1.w);  o3.y = pack2(v2.w, v3.w);

    bf16* q = op + (size_t)(c0 + c) * R + r0 + r;
    *(uint2*)(q)       = o0;
    *(uint2*)(q + R)   = o1;
    *(uint2*)(q + 2*R) = o2;
    *(uint2*)(q + 3*R) = o3;
}

// ---------------- gather tokens into compacted bf16 A-matrix ----------------
__global__ __launch_bounds__(256) void gather_kernel(
    const float* __restrict__ x, const int* __restrict__ cnt, const int* __restrict__ off,
    const int* __restrict__ tok_list, bf16* __restrict__ Xg)
{
    int bx = blockIdx.x;
    int e  = bx >> 12;
    int i  = bx & 4095;
    if (i >= cnt[e]) return;
    int tok = tok_list[e*NTOK + i];
    size_t row = (size_t)(off[e] + i);
    int t = threadIdx.x;
    float4 v = *(const float4*)(x + (size_t)tok * D_ + t*4);
    uint2 uu;
    uu.x = pack2(v.x, v.y);
    uu.y = pack2(v.z, v.w);
    *(uint2*)(Xg + row * D_ + t*4) = uu;
}

// ============ GEMM1: H = gelu(Xg @ W1 + b1), bf16 out ============
__global__ __launch_bounds__(256) void gemm1_kernel(
    const bf16* __restrict__ Xg, const bf16* __restrict__ W1t,
    const float* __restrict__ b1, const int* __restrict__ cnt,
    const int* __restrict__ off, bf16* __restrict__ H)
{
    int bx = blockIdx.x;
    int e  = bx >> 10;
    int r2 = bx & 1023;
    int mtile = r2 >> 5, ntile = r2 & 31;
    int n = cnt[e];
    if (mtile * 128 >= n) return;
    int row0 = off[e] + mtile * 128;
    int f0 = ntile * 128;

    __shared__ bf16 As[128*64];
    __shared__ bf16 Bs[128*64];

    int t = threadIdx.x;
    int wave = t >> 6, lane = t & 63;
    int wm = wave & 1, wn = wave >> 1;
    int q = lane >> 4, ln = lane & 15;
    int sm = lane >> 3, sc = lane & 7;

    const bf16* Abase = Xg  + (size_t)row0 * D_;
    const bf16* Bbase = W1t + ((size_t)e * F_ + f0) * D_;

    floatx4 acc[4][4];
#pragma unroll
    for (int mt = 0; mt < 4; ++mt)
#pragma unroll
        for (int nt = 0; nt < 4; ++nt) acc[mt][nt] = {0.f, 0.f, 0.f, 0.f};

    for (int kt = 0; kt < D_; kt += 64) {
        __syncthreads();
#pragma unroll
        for (int i = 0; i < 4; ++i) {
            int g = wave*4 + i;
            int m = g*8 + sm;
            int ca = sc ^ (m & 7);
            async_load16(Abase + (size_t)m * D_ + kt + ca*8, &As[g*512]);
            async_load16(Bbase + (size_t)m * D_ + kt + ca*8, &Bs[g*512]);
        }
        __syncthreads();
#pragma unroll
        for (int kk = 0; kk < 2; ++kk) {
            short8 av[4], bv[4];
#pragma unroll
            for (int mt = 0; mt < 4; ++mt) {
                int r = wm*64 + mt*16 + ln;
                int cs = (kk*4 + q) ^ (r & 7);
                av[mt] = *(const short8*)&As[r*64 + cs*8];
            }
#pragma unroll
            for (int nt = 0; nt < 4; ++nt) {
                int r = wn*64 + nt*16 + ln;
                int cs = (kk*4 + q) ^ (r & 7);
                bv[nt] = *(const short8*)&Bs[r*64 + cs*8];
            }
#pragma unroll
            for (int mt = 0; mt < 4; ++mt)
#pragma unroll
                for (int nt = 0; nt < 4; ++nt)
                    acc[mt][nt] = __builtin_amdgcn_mfma_f32_16x16x32_bf16(av[mt], bv[nt], acc[mt][nt], 0, 0, 0);
        }
    }

    const float is2 = 0.70710678118654752f;
#pragma unroll
    for (int nt = 0; nt < 4; ++nt) {
        int f = f0 + wn*64 + nt*16 + ln;
        float b1v = b1[(size_t)e * F_ + f];
#pragma unroll
        for (int mt = 0; mt < 4; ++mt) {
            int rl = wm*64 + mt*16 + q*4;
#pragma unroll
            for (int r = 0; r < 4; ++r) {
                float v = acc[mt][nt][r] + b1v;
                v = 0.5f * v * (1.f + erff(v * is2));
                H[(size_t)(row0 + rl + r) * F_ + f] = __float2bfloat16(v);
            }
        }
    }
}

// ============ GEMM2 (split-K x2): out[tok] += w * (H @ W2 [+ b2 on ks==0]) ============
__global__ __launch_bounds__(256) void gemm2_kernel(
    const bf16* __restrict__ H, const bf16* __restrict__ W2t,
    const float* __restrict__ b2, const int* __restrict__ cnt, const int* __restrict__ off,
    const int* __restrict__ tok_list, const float* __restrict__ w_list,
    float* __restrict__ out)
{
    int bx = blockIdx.x;
    int e   = bx >> 9;           // 32 mtiles * 8 ntiles * 2 ksplits per expert
    int rem = bx & 511;
    int mtile = rem >> 4;
    int ntile = (rem >> 1) & 7;
    int ks    = rem & 1;
    int n = cnt[e];
    if (mtile * 128 >= n) return;
    int row0 = off[e] + mtile * 128;
    int d0 = ntile * 128;
    int kt0 = ks * (F_/2);

    __shared__ bf16 As[128*64];
    __shared__ bf16 Bs[128*64];

    int t = threadIdx.x;
    int wave = t >> 6, lane = t & 63;
    int wm = wave & 1, wn = wave >> 1;
    int q = lane >> 4, ln = lane & 15;
    int sm = lane >> 3, sc = lane & 7;

    const bf16* Abase = H   + (size_t)row0 * F_;
    const bf16* Bbase = W2t + ((size_t)e * D_ + d0) * F_;

    floatx4 acc[4][4];
#pragma unroll
    for (int mt = 0; mt < 4; ++mt)
#pragma unroll
        for (int nt = 0; nt < 4; ++nt) acc[mt][nt] = {0.f, 0.f, 0.f, 0.f};

    for (int kt = kt0; kt < kt0 + F_/2; kt += 64) {
        __syncthreads();
#pragma unroll
        for (int i = 0; i < 4; ++i) {
            int g = wave*4 + i;
            int m = g*8 + sm;
            int ca = sc ^ (m & 7);
            async_load16(Abase + (size_t)m * F_ + kt + ca*8, &As[g*512]);
            async_load16(Bbase + (size_t)m * F_ + kt + ca*8, &Bs[g*512]);
        }
        __syncthreads();
#pragma unroll
        for (int kk = 0; kk < 2; ++kk) {
            short8 av[4], bv[4];
#pragma unroll
            for (int mt = 0; mt < 4; ++mt) {
                int r = wm*64 + mt*16 + ln;
                int cs = (kk*4 + q) ^ (r & 7);
                av[mt] = *(const short8*)&As[r*64 + cs*8];
            }
#pragma unroll
            for (int nt = 0; nt < 4; ++nt) {
                int r = wn*64 + nt*16 + ln;
                int cs = (kk*4 + q) ^ (r & 7);
                bv[nt] = *(const short8*)&Bs[r*64 + cs*8];
            }
#pragma unroll
            for (int mt = 0; mt < 4; ++mt)
#pragma unroll
                for (int nt = 0; nt < 4; ++nt)
                    acc[mt][nt] = __builtin_amdgcn_mfma_f32_16x16x32_bf16(av[mt], bv[nt], acc[mt][nt], 0, 0, 0);
        }
    }

    float b2v[4];
#pragma unroll
    for (int nt = 0; nt < 4; ++nt)
        b2v[nt] = (ks == 0) ? b2[(size_t)e * D_ + d0 + wn*64 + nt*16 + ln] : 0.f;

#pragma unroll
    for (int mt = 0; mt < 4; ++mt) {
#pragma unroll
        for (int r = 0; r < 4; ++r) {
            int i = mtile*128 + wm*64 + mt*16 + q*4 + r;
            if (i < n) {
                int tok = tok_list[e*NTOK + i];
                float w = w_list[e*NTOK + i];
                float* op = out + (size_t)tok * D_;
#pragma unroll
                for (int nt = 0; nt < 4; ++nt) {
                    int d = d0 + wn*64 + nt*16 + ln;
                    atomicAdd(op + d, w * (acc[mt][nt][r] + b2v[nt]));
                }
            }
        }
    }
}

extern "C" void kernel_launch(void* const* d_in, const int* in_sizes, int n_in,
                              void* d_out, int out_size, void* d_ws, size_t ws_size,
                              hipStream_t stream)
{
    const float* x  = (const float*)d_in[0];
    const float* Wg = (const float*)d_in[1];
    const float* bg = (const float*)d_in[2];
    const float* W1 = (const float*)d_in[3];
    const float* b1 = (const float*)d_in[4];
    const float* W2 = (const float*)d_in[5];
    const float* b2 = (const float*)d_in[6];
    float* out = (float*)d_out;

    char* ws = (char*)d_ws;
    int*      cnt      = (int*)(ws + 0);
    int*      off      = (int*)(ws + 128);
    float*    psum_pad = (float*)(ws + 1024);
    uint32_t* top_ids  = (uint32_t*)(ws + 8192);
    float*    top_w    = (float*)(ws + 8192 + 16384);
    int*      tok_list = (int*)(ws + 65536);
    float*    w_list   = (float*)(ws + 65536 + 131072);
    size_t o = 1u << 20;
    bf16*  W1t = (bf16*)(ws + o);  o += (size_t)E_ * D_ * F_ * 2;   // 64 MB
    bf16*  W2t = (bf16*)(ws + o);  o += (size_t)E_ * F_ * D_ * 2;   // 64 MB
    bf16*  Xg  = (bf16*)(ws + o);  o += (size_t)MAXROWS * D_ * 2;   // 18 MB
    bf16*  H   = (bf16*)(ws + o);                                    // 72 MB

    hipMemsetAsync(d_out, 0, (size_t)out_size * sizeof(float), stream);
    hipMemsetAsync(ws + 1024, 0, 1024, stream);   // psum_pad

    transpose_bf16_kernel<<<E_ * 16 * 64, 256, 0, stream>>>(W1, W1t, D_, F_);  // -> [E][F][D]
    transpose_bf16_kernel<<<E_ * 64 * 16, 256, 0, stream>>>(W2, W2t, F_, D_);  // -> [E][D][F]

    gate_kernel<<<256, 256, 0, stream>>>(x, Wg, bg, psum_pad, top_ids, top_w);
    compact_kernel<<<E_, 256, 0, stream>>>(top_ids, top_w, cnt, tok_list, w_list);
    finalize_gate_kernel<<<1, 1, 0, stream>>>(cnt, psum_pad, off, out + (size_t)NTOK * D_);
    gather_kernel<<<E_ * 4096, 256, 0, stream>>>(x, cnt, off, tok_list, Xg);

    gemm1_kernel<<<E_ * 32 * 32, 256, 0, stream>>>(Xg, W1t, b1, cnt, off, H);
    gemm2_kernel<<<E_ * 32 * 8 * 2, 256, 0, stream>>>(H, W2t, b2, cnt, off, tok_list, w_list, out);
}

// Round 5
// 684.622 us; speedup vs baseline: 1.0220x; 1.0220x over previous
//
#include <hip/hip_runtime.h>
#include <hip/hip_bf16.h>
#include <cstdint>
#include <cstddef>

// B=2, L=2048, D=1024, F=4096, E=8, K=2
#define B_ 2
#define L_ 2048
#define D_ 1024
#define F_ 4096
#define E_ 8
#define NTOK 4096
#define MAXROWS 9216   // sum over experts of pad128(n_e) <= 8192 + 8*127

typedef __hip_bfloat16 bf16;
typedef __attribute__((ext_vector_type(8))) short short8;
typedef __attribute__((ext_vector_type(4))) float floatx4;

typedef const __attribute__((address_space(1))) uint32_t* gptr_t;
typedef __attribute__((address_space(3))) uint32_t* lptr_t;

__device__ __forceinline__ void async_load16(const bf16* gp, bf16* lp) {
    __builtin_amdgcn_global_load_lds((gptr_t)(const void*)gp, (lptr_t)(void*)lp, 16, 0, 0);
}

__device__ __forceinline__ uint16_t bfbits(bf16 h) {
    union { bf16 b; uint16_t u; } v; v.b = h; return v.u;
}
__device__ __forceinline__ uint32_t pack2(float a, float b) {
    return (uint32_t)bfbits(__float2bfloat16(a)) | ((uint32_t)bfbits(__float2bfloat16(b)) << 16);
}
__device__ __forceinline__ float ublo(uint32_t u){ return __uint_as_float(u << 16); }
__device__ __forceinline__ float ubhi(uint32_t u){ return __uint_as_float(u & 0xffff0000u); }

// ---------------- gating: 256 blocks x 256 thr, 16 tokens/block (4/wave) ----------------
__global__ __launch_bounds__(256) void gate_kernel(
    const float* __restrict__ x, const float* __restrict__ Wg,
    const float* __restrict__ bg, float* __restrict__ psum_pad,
    uint32_t* __restrict__ top_ids, float* __restrict__ top_w)
{
    __shared__ float psum_l[E_];
    int t = threadIdx.x;
    if (t < E_) psum_l[t] = 0.f;
    __syncthreads();

    int wave = t >> 6, lane = t & 63;
    for (int j = 0; j < 4; ++j) {
        int token = blockIdx.x * 16 + wave * 4 + j;
        const float* xr = x + (size_t)token * D_;

        float acc[E_];
#pragma unroll
        for (int e = 0; e < E_; ++e) acc[e] = 0.f;
        for (int i = 0; i < D_/64; ++i) {
            int d = lane + 64*i;
            float xv = xr[d];
            const float4* wr4 = (const float4*)(Wg + (size_t)d * E_);
            float4 wa = wr4[0], wb = wr4[1];
            acc[0] += xv * wa.x;  acc[1] += xv * wa.y;
            acc[2] += xv * wa.z;  acc[3] += xv * wa.w;
            acc[4] += xv * wb.x;  acc[5] += xv * wb.y;
            acc[6] += xv * wb.z;  acc[7] += xv * wb.w;
        }
#pragma unroll
        for (int off = 32; off >= 1; off >>= 1) {
#pragma unroll
            for (int e = 0; e < E_; ++e) acc[e] += __shfl_xor(acc[e], off, 64);
        }
        if (lane == 0) {
            float s[E_];
#pragma unroll
            for (int e = 0; e < E_; ++e) s[e] = acc[e] + bg[e];
            int i0 = 0;
#pragma unroll
            for (int e = 1; e < E_; ++e) if (s[e] > s[i0]) i0 = e;
            int i1 = -1;
#pragma unroll
            for (int e = 0; e < E_; ++e) {
                if (e == i0) continue;
                if (i1 < 0 || s[e] > s[i1]) i1 = e;
            }
            float e1 = expf(s[i1] - s[i0]);
            float w0 = 1.f / (1.f + e1);
            float w1 = e1 * w0;
            top_ids[token] = (uint32_t)i0 | ((uint32_t)i1 << 8);
            top_w[token]        = w0;
            top_w[NTOK + token] = w1;

            float mx = s[i0], p[E_], sum = 0.f;
#pragma unroll
            for (int e = 0; e < E_; ++e) { p[e] = expf(s[e] - mx); sum += p[e]; }
            float inv = 1.f / sum;
#pragma unroll
            for (int e = 0; e < E_; ++e) atomicAdd(&psum_l[e], p[e] * inv);
        }
    }
    __syncthreads();
    if (t < E_) atomicAdd(&psum_pad[t * 32], psum_l[t]);
}

// ---------------- deterministic per-expert compaction + inverse index ----------------
__global__ __launch_bounds__(256) void compact_kernel(
    const uint32_t* __restrict__ top_ids, const float* __restrict__ top_w,
    int* __restrict__ cnt, int* __restrict__ tok_list, float* __restrict__ w_list,
    int* __restrict__ rowid)
{
    int e = blockIdx.x;
    int t = threadIdx.x, wave = t >> 6, lane = t & 63;
    __shared__ int wcnt[4];
    int base = 0;
    for (int r0 = 0; r0 < NTOK; r0 += 256) {
        int token = r0 + t;
        uint32_t ids = top_ids[token];
        int slot = -1;
        if ((int)(ids & 255u) == e) slot = 0;
        else if ((int)((ids >> 8) & 255u) == e) slot = 1;
        unsigned long long mask = __ballot(slot >= 0);
        int lpos = __popcll(mask & ((1ull << lane) - 1ull));
        if (lane == 0) wcnt[wave] = (int)__popcll(mask);
        __syncthreads();
        int woff = 0, tot = 0;
#pragma unroll
        for (int w2 = 0; w2 < 4; ++w2) { if (w2 < wave) woff += wcnt[w2]; tot += wcnt[w2]; }
        if (slot >= 0) {
            int pos = base + woff + lpos;
            tok_list[e*NTOK + pos] = token;
            w_list[e*NTOK + pos]   = top_w[slot*NTOK + token];
            rowid[slot*NTOK + token] = (e << 13) | pos;   // inverse index for combine
        }
        base += tot;
        __syncthreads();
    }
    if (t == 0) cnt[e] = base;
}

// ---------------- finalize: padded prefix offsets + loss ----------------
__global__ void finalize_gate_kernel(const int* __restrict__ cnt, const float* __restrict__ psum_pad,
                                     int* __restrict__ off, float* __restrict__ loss_out)
{
    int o = 0; float Ls = 0.f;
    for (int e = 0; e < E_; ++e) {
        off[e] = o;
        o += (cnt[e] + 127) & ~127;
        Ls += (float)cnt[e] * psum_pad[e * 32];
    }
    loss_out[0] = (float)E_ * Ls / ((float)NTOK * (float)NTOK);
}

// ---------------- weight transpose+convert v2: 128x64 tiles, 8x4 micro-tile/thread ----------------
// [R][C] f32 -> [C][R] bf16 per expert. Coalesced 256B row loads, 16B output stores.
__global__ __launch_bounds__(256) void transpose_bf16_kernel(
    const float* __restrict__ in, bf16* __restrict__ outp, int R, int C)
{
    int tilesR = R >> 7, tilesC = C >> 6;
    int per = tilesR * tilesC;
    int bx = blockIdx.x;
    int e  = bx / per; int r2 = bx % per;
    int tr = r2 / tilesC, tc = r2 % tilesC;
    int r0 = tr << 7, c0 = tc << 6;
    const float* ip = in  + (size_t)e * R * C;
    bf16*        op = outp + (size_t)e * R * C;

    int t = threadIdx.x;
    int c = (t & 15) * 4;   // col within tile
    int r = (t >> 4) * 8;   // row within tile

    const float* p = ip + (size_t)(r0 + r) * C + c0 + c;
    float4 v[8];
#pragma unroll
    for (int j = 0; j < 8; ++j) v[j] = *(const float4*)(p + (size_t)j * C);
    const float* vf = (const float*)v;

#pragma unroll
    for (int i = 0; i < 4; ++i) {
        uint4 o;
        o.x = pack2(vf[0*4+i], vf[1*4+i]);
        o.y = pack2(vf[2*4+i], vf[3*4+i]);
        o.z = pack2(vf[4*4+i], vf[5*4+i]);
        o.w = pack2(vf[6*4+i], vf[7*4+i]);
        *(uint4*)(op + (size_t)(c0 + c + i) * R + r0 + r) = o;
    }
}

// ---------------- gather tokens into compacted bf16 A-matrix ----------------
__global__ __launch_bounds__(256) void gather_kernel(
    const float* __restrict__ x, const int* __restrict__ cnt, const int* __restrict__ off,
    const int* __restrict__ tok_list, bf16* __restrict__ Xg)
{
    int bx = blockIdx.x;
    int e  = bx >> 12;
    int i  = bx & 4095;
    if (i >= cnt[e]) return;
    int tok = tok_list[e*NTOK + i];
    size_t row = (size_t)(off[e] + i);
    int t = threadIdx.x;
    float4 v = *(const float4*)(x + (size_t)tok * D_ + t*4);
    uint2 uu;
    uu.x = pack2(v.x, v.y);
    uu.y = pack2(v.z, v.w);
    *(uint2*)(Xg + row * D_ + t*4) = uu;
}

// ============ GEMM1: H = gelu(Xg @ W1 + b1), bf16 out ============
__global__ __launch_bounds__(256) void gemm1_kernel(
    const bf16* __restrict__ Xg, const bf16* __restrict__ W1t,
    const float* __restrict__ b1, const int* __restrict__ cnt,
    const int* __restrict__ off, bf16* __restrict__ H)
{
    int bx = blockIdx.x;
    int e  = bx >> 10;
    int r2 = bx & 1023;
    int mtile = r2 >> 5, ntile = r2 & 31;
    int n = cnt[e];
    if (mtile * 128 >= n) return;
    int row0 = off[e] + mtile * 128;
    int f0 = ntile * 128;

    __shared__ bf16 As[128*64];
    __shared__ bf16 Bs[128*64];

    int t = threadIdx.x;
    int wave = t >> 6, lane = t & 63;
    int wm = wave & 1, wn = wave >> 1;
    int q = lane >> 4, ln = lane & 15;
    int sm = lane >> 3, sc = lane & 7;

    const bf16* Abase = Xg  + (size_t)row0 * D_;
    const bf16* Bbase = W1t + ((size_t)e * F_ + f0) * D_;

    floatx4 acc[4][4];
#pragma unroll
    for (int mt = 0; mt < 4; ++mt)
#pragma unroll
        for (int nt = 0; nt < 4; ++nt) acc[mt][nt] = {0.f, 0.f, 0.f, 0.f};

    for (int kt = 0; kt < D_; kt += 64) {
        __syncthreads();
#pragma unroll
        for (int i = 0; i < 4; ++i) {
            int g = wave*4 + i;
            int m = g*8 + sm;
            int ca = sc ^ (m & 7);
            async_load16(Abase + (size_t)m * D_ + kt + ca*8, &As[g*512]);
            async_load16(Bbase + (size_t)m * D_ + kt + ca*8, &Bs[g*512]);
        }
        __syncthreads();
#pragma unroll
        for (int kk = 0; kk < 2; ++kk) {
            short8 av[4], bv[4];
#pragma unroll
            for (int mt = 0; mt < 4; ++mt) {
                int r = wm*64 + mt*16 + ln;
                int cs = (kk*4 + q) ^ (r & 7);
                av[mt] = *(const short8*)&As[r*64 + cs*8];
            }
#pragma unroll
            for (int nt = 0; nt < 4; ++nt) {
                int r = wn*64 + nt*16 + ln;
                int cs = (kk*4 + q) ^ (r & 7);
                bv[nt] = *(const short8*)&Bs[r*64 + cs*8];
            }
#pragma unroll
            for (int mt = 0; mt < 4; ++mt)
#pragma unroll
                for (int nt = 0; nt < 4; ++nt)
                    acc[mt][nt] = __builtin_amdgcn_mfma_f32_16x16x32_bf16(av[mt], bv[nt], acc[mt][nt], 0, 0, 0);
        }
    }

    const float is2 = 0.70710678118654752f;
#pragma unroll
    for (int nt = 0; nt < 4; ++nt) {
        int f = f0 + wn*64 + nt*16 + ln;
        float b1v = b1[(size_t)e * F_ + f];
#pragma unroll
        for (int mt = 0; mt < 4; ++mt) {
            int rl = wm*64 + mt*16 + q*4;
#pragma unroll
            for (int r = 0; r < 4; ++r) {
                float v = acc[mt][nt][r] + b1v;
                v = 0.5f * v * (1.f + erff(v * is2));
                H[(size_t)(row0 + rl + r) * F_ + f] = __float2bfloat16(v);
            }
        }
    }
}

// ============ GEMM2: Y[row] = H @ W2 + b2 (bf16, plain stores; no atomics) ============
__global__ __launch_bounds__(256) void gemm2_kernel(
    const bf16* __restrict__ H, const bf16* __restrict__ W2t,
    const float* __restrict__ b2, const int* __restrict__ cnt, const int* __restrict__ off,
    bf16* __restrict__ Y)
{
    int bx = blockIdx.x;
    int e   = bx >> 8;           // 32 mtiles * 8 ntiles per expert
    int rem = bx & 255;
    int mtile = rem >> 3;
    int ntile = rem & 7;
    int n = cnt[e];
    if (mtile * 128 >= n) return;
    int row0 = off[e] + mtile * 128;
    int d0 = ntile * 128;

    __shared__ bf16 As[128*64];
    __shared__ bf16 Bs[128*64];

    int t = threadIdx.x;
    int wave = t >> 6, lane = t & 63;
    int wm = wave & 1, wn = wave >> 1;
    int q = lane >> 4, ln = lane & 15;
    int sm = lane >> 3, sc = lane & 7;

    const bf16* Abase = H   + (size_t)row0 * F_;
    const bf16* Bbase = W2t + ((size_t)e * D_ + d0) * F_;

    floatx4 acc[4][4];
#pragma unroll
    for (int mt = 0; mt < 4; ++mt)
#pragma unroll
        for (int nt = 0; nt < 4; ++nt) acc[mt][nt] = {0.f, 0.f, 0.f, 0.f};

    for (int kt = 0; kt < F_; kt += 64) {
        __syncthreads();
#pragma unroll
        for (int i = 0; i < 4; ++i) {
            int g = wave*4 + i;
            int m = g*8 + sm;
            int ca = sc ^ (m & 7);
            async_load16(Abase + (size_t)m * F_ + kt + ca*8, &As[g*512]);
            async_load16(Bbase + (size_t)m * F_ + kt + ca*8, &Bs[g*512]);
        }
        __syncthreads();
#pragma unroll
        for (int kk = 0; kk < 2; ++kk) {
            short8 av[4], bv[4];
#pragma unroll
            for (int mt = 0; mt < 4; ++mt) {
                int r = wm*64 + mt*16 + ln;
                int cs = (kk*4 + q) ^ (r & 7);
                av[mt] = *(const short8*)&As[r*64 + cs*8];
            }
#pragma unroll
            for (int nt = 0; nt < 4; ++nt) {
                int r = wn*64 + nt*16 + ln;
                int cs = (kk*4 + q) ^ (r & 7);
                bv[nt] = *(const short8*)&Bs[r*64 + cs*8];
            }
#pragma unroll
            for (int mt = 0; mt < 4; ++mt)
#pragma unroll
                for (int nt = 0; nt < 4; ++nt)
                    acc[mt][nt] = __builtin_amdgcn_mfma_f32_16x16x32_bf16(av[mt], bv[nt], acc[mt][nt], 0, 0, 0);
        }
    }

    float b2v[4];
#pragma unroll
    for (int nt = 0; nt < 4; ++nt)
        b2v[nt] = b2[(size_t)e * D_ + d0 + wn*64 + nt*16 + ln];

#pragma unroll
    for (int mt = 0; mt < 4; ++mt) {
#pragma unroll
        for (int r = 0; r < 4; ++r) {
            int loc = wm*64 + mt*16 + q*4 + r;
            int i = mtile*128 + loc;
            if (i < n) {
                bf16* yp = Y + (size_t)(row0 + loc) * D_ + d0;
#pragma unroll
                for (int nt = 0; nt < 4; ++nt)
                    yp[wn*64 + nt*16 + ln] = __float2bfloat16(acc[mt][nt][r] + b2v[nt]);
            }
        }
    }
}

// ---------------- combine: out[tok] = w0*Y[row0] + w1*Y[row1] ----------------
__global__ __launch_bounds__(256) void combine_kernel(
    const bf16* __restrict__ Y, const int* __restrict__ rowid,
    const float* __restrict__ top_w, const int* __restrict__ off,
    float* __restrict__ out)
{
    int tok = blockIdx.x;
    int t = threadIdx.x;
    int v0 = rowid[tok], v1 = rowid[NTOK + tok];
    float w0 = top_w[tok], w1 = top_w[NTOK + tok];
    size_t r0 = (size_t)(off[v0 >> 13] + (v0 & 8191));
    size_t r1 = (size_t)(off[v1 >> 13] + (v1 & 8191));
    uint2 a = *(const uint2*)(Y + r0 * D_ + t*4);
    uint2 b = *(const uint2*)(Y + r1 * D_ + t*4);
    float4 o;
    o.x = w0 * ublo(a.x) + w1 * ublo(b.x);
    o.y = w0 * ubhi(a.x) + w1 * ubhi(b.x);
    o.z = w0 * ublo(a.y) + w1 * ublo(b.y);
    o.w = w0 * ubhi(a.y) + w1 * ubhi(b.y);
    *(float4*)(out + (size_t)tok * D_ + t*4) = o;
}

extern "C" void kernel_launch(void* const* d_in, const int* in_sizes, int n_in,
                              void* d_out, int out_size, void* d_ws, size_t ws_size,
                              hipStream_t stream)
{
    const float* x  = (const float*)d_in[0];
    const float* Wg = (const float*)d_in[1];
    const float* bg = (const float*)d_in[2];
    const float* W1 = (const float*)d_in[3];
    const float* b1 = (const float*)d_in[4];
    const float* W2 = (const float*)d_in[5];
    const float* b2 = (const float*)d_in[6];
    float* out = (float*)d_out;

    char* ws = (char*)d_ws;
    int*      cnt      = (int*)(ws + 0);
    int*      off      = (int*)(ws + 128);
    float*    psum_pad = (float*)(ws + 1024);
    uint32_t* top_ids  = (uint32_t*)(ws + 8192);
    float*    top_w    = (float*)(ws + 8192 + 16384);
    int*      tok_list = (int*)(ws + 65536);
    float*    w_list   = (float*)(ws + 65536 + 131072);
    int*      rowid    = (int*)(ws + 327680);            // [2][NTOK]
    size_t o = 1u << 20;
    bf16*  W1t = (bf16*)(ws + o);  o += (size_t)E_ * D_ * F_ * 2;   // 64 MB
    bf16*  W2t = (bf16*)(ws + o);  o += (size_t)E_ * F_ * D_ * 2;   // 64 MB
    bf16*  Xg  = (bf16*)(ws + o);  o += (size_t)MAXROWS * D_ * 2;   // 18.9 MB
    bf16*  H   = (bf16*)(ws + o);                                    // 75.5 MB
    bf16*  Y   = Xg;   // alias: Xg is dead after gemm1; Y written by gemm2 (same size/shape)

    hipMemsetAsync(ws + 1024, 0, 1024, stream);   // psum_pad

    transpose_bf16_kernel<<<E_ * 8 * 64, 256, 0, stream>>>(W1, W1t, D_, F_);   // -> [E][F][D]
    transpose_bf16_kernel<<<E_ * 32 * 16, 256, 0, stream>>>(W2, W2t, F_, D_);  // -> [E][D][F]

    gate_kernel<<<256, 256, 0, stream>>>(x, Wg, bg, psum_pad, top_ids, top_w);
    compact_kernel<<<E_, 256, 0, stream>>>(top_ids, top_w, cnt, tok_list, w_list, rowid);
    finalize_gate_kernel<<<1, 1, 0, stream>>>(cnt, psum_pad, off, out + (size_t)NTOK * D_);
    gather_kernel<<<E_ * 4096, 256, 0, stream>>>(x, cnt, off, tok_list, Xg);

    gemm1_kernel<<<E_ * 32 * 32, 256, 0, stream>>>(Xg, W1t, b1, cnt, off, H);
    gemm2_kernel<<<E_ * 32 * 8, 256, 0, stream>>>(H, W2t, b2, cnt, off, Y);
    combine_kernel<<<NTOK, 256, 0, stream>>>(Y, rowid, top_w, off, out);
}

// Round 6
// 659.859 us; speedup vs baseline: 1.0603x; 1.0375x over previous
//
#include <hip/hip_runtime.h>
#include <hip/hip_bf16.h>
#include <cstdint>
#include <cstddef>

// B=2, L=2048, D=1024, F=4096, E=8, K=2
#define B_ 2
#define L_ 2048
#define D_ 1024
#define F_ 4096
#define E_ 8
#define NTOK 4096
#define MAXROWS 9216   // sum over experts of pad128(n_e) <= 8192 + 8*127

typedef __hip_bfloat16 bf16;
typedef __attribute__((ext_vector_type(8))) short short8;
typedef __attribute__((ext_vector_type(4))) float floatx4;

typedef const __attribute__((address_space(1))) uint32_t* gptr_t;
typedef __attribute__((address_space(3))) uint32_t* lptr_t;

__device__ __forceinline__ void async_load16(const bf16* gp, bf16* lp) {
    __builtin_amdgcn_global_load_lds((gptr_t)(const void*)gp, (lptr_t)(void*)lp, 16, 0, 0);
}

__device__ __forceinline__ uint16_t bfbits(bf16 h) {
    union { bf16 b; uint16_t u; } v; v.b = h; return v.u;
}
__device__ __forceinline__ uint32_t pack2(float a, float b) {
    return (uint32_t)bfbits(__float2bfloat16(a)) | ((uint32_t)bfbits(__float2bfloat16(b)) << 16);
}
__device__ __forceinline__ float ublo(uint32_t u){ return __uint_as_float(u << 16); }
__device__ __forceinline__ float ubhi(uint32_t u){ return __uint_as_float(u & 0xffff0000u); }

// tanh-form GELU: x * sigmoid(2*sqrt(2/pi)*(x + 0.044715 x^3)); max |err| vs exact ~3e-4
__device__ __forceinline__ float fast_gelu(float x) {
    float x2 = x * x;
    float z = x * fmaf(0.1029432f, x2, 2.3022081f);   // 2*log2(e)*0.7978845608*(1, 0.044715)
    z = fminf(z, 120.f);                               // avoid inf/inf
    float u = __builtin_amdgcn_exp2f(z);
    return x * u * __builtin_amdgcn_rcpf(1.f + u);
}

// ---------------- gating: 256 blocks x 256 thr, 16 tokens/block (4/wave) ----------------
__global__ __launch_bounds__(256) void gate_kernel(
    const float* __restrict__ x, const float* __restrict__ Wg,
    const float* __restrict__ bg, float* __restrict__ psum_pad,
    uint32_t* __restrict__ top_ids, float* __restrict__ top_w)
{
    __shared__ float psum_l[E_];
    int t = threadIdx.x;
    if (t < E_) psum_l[t] = 0.f;
    __syncthreads();

    int wave = t >> 6, lane = t & 63;
    for (int j = 0; j < 4; ++j) {
        int token = blockIdx.x * 16 + wave * 4 + j;
        const float* xr = x + (size_t)token * D_;

        float acc[E_];
#pragma unroll
        for (int e = 0; e < E_; ++e) acc[e] = 0.f;
#pragma unroll
        for (int i = 0; i < 4; ++i) {
            int d = lane * 4 + 256 * i;
            float4 xv = *(const float4*)(xr + d);
            const float* xs = &xv.x;
#pragma unroll
            for (int jj = 0; jj < 4; ++jj) {
                const float4* wr4 = (const float4*)(Wg + (size_t)(d + jj) * E_);
                float4 wa = wr4[0], wb = wr4[1];
                float xvj = xs[jj];
                acc[0] += xvj * wa.x;  acc[1] += xvj * wa.y;
                acc[2] += xvj * wa.z;  acc[3] += xvj * wa.w;
                acc[4] += xvj * wb.x;  acc[5] += xvj * wb.y;
                acc[6] += xvj * wb.z;  acc[7] += xvj * wb.w;
            }
        }
#pragma unroll
        for (int off = 32; off >= 1; off >>= 1) {
#pragma unroll
            for (int e = 0; e < E_; ++e) acc[e] += __shfl_xor(acc[e], off, 64);
        }
        if (lane == 0) {
            float s[E_];
#pragma unroll
            for (int e = 0; e < E_; ++e) s[e] = acc[e] + bg[e];
            int i0 = 0;
#pragma unroll
            for (int e = 1; e < E_; ++e) if (s[e] > s[i0]) i0 = e;
            int i1 = -1;
#pragma unroll
            for (int e = 0; e < E_; ++e) {
                if (e == i0) continue;
                if (i1 < 0 || s[e] > s[i1]) i1 = e;
            }
            float e1 = expf(s[i1] - s[i0]);
            float w0 = 1.f / (1.f + e1);
            float w1 = e1 * w0;
            top_ids[token] = (uint32_t)i0 | ((uint32_t)i1 << 8);
            top_w[token]        = w0;
            top_w[NTOK + token] = w1;

            float mx = s[i0], p[E_], sum = 0.f;
#pragma unroll
            for (int e = 0; e < E_; ++e) { p[e] = expf(s[e] - mx); sum += p[e]; }
            float inv = 1.f / sum;
#pragma unroll
            for (int e = 0; e < E_; ++e) atomicAdd(&psum_l[e], p[e] * inv);
        }
    }
    __syncthreads();
    if (t < E_) atomicAdd(&psum_pad[t * 32], psum_l[t]);
}

// ---------------- deterministic per-expert compaction + inverse index ----------------
__global__ __launch_bounds__(256) void compact_kernel(
    const uint32_t* __restrict__ top_ids, const float* __restrict__ top_w,
    int* __restrict__ cnt, int* __restrict__ tok_list, float* __restrict__ w_list,
    int* __restrict__ rowid)
{
    int e = blockIdx.x;
    int t = threadIdx.x, wave = t >> 6, lane = t & 63;
    __shared__ int wcnt[4];
    int base = 0;
    for (int r0 = 0; r0 < NTOK; r0 += 256) {
        int token = r0 + t;
        uint32_t ids = top_ids[token];
        int slot = -1;
        if ((int)(ids & 255u) == e) slot = 0;
        else if ((int)((ids >> 8) & 255u) == e) slot = 1;
        unsigned long long mask = __ballot(slot >= 0);
        int lpos = __popcll(mask & ((1ull << lane) - 1ull));
        if (lane == 0) wcnt[wave] = (int)__popcll(mask);
        __syncthreads();
        int woff = 0, tot = 0;
#pragma unroll
        for (int w2 = 0; w2 < 4; ++w2) { if (w2 < wave) woff += wcnt[w2]; tot += wcnt[w2]; }
        if (slot >= 0) {
            int pos = base + woff + lpos;
            tok_list[e*NTOK + pos] = token;
            w_list[e*NTOK + pos]   = top_w[slot*NTOK + token];
            rowid[slot*NTOK + token] = (e << 13) | pos;   // inverse index for combine
        }
        base += tot;
        __syncthreads();
    }
    if (t == 0) cnt[e] = base;
}

// ---------------- finalize: padded prefix offsets + loss ----------------
__global__ void finalize_gate_kernel(const int* __restrict__ cnt, const float* __restrict__ psum_pad,
                                     int* __restrict__ off, float* __restrict__ loss_out)
{
    int o = 0; float Ls = 0.f;
    for (int e = 0; e < E_; ++e) {
        off[e] = o;
        o += (cnt[e] + 127) & ~127;
        Ls += (float)cnt[e] * psum_pad[e * 32];
    }
    loss_out[0] = (float)E_ * Ls / ((float)NTOK * (float)NTOK);
}

// ---------------- weight transpose+convert v3: LDS row-pair packing ----------------
// [R][C] f32 -> [C][R] bf16 per expert, 64x64 tiles.
// Phase 1: pack vertical pairs (r,r+1) into uint32, LDS T[col][pair] (2-way-free banks).
// Phase 2: uint4 reads per output row -> 16B stores, 8 lanes cover a full 128B row/instr.
__global__ __launch_bounds__(256) void transpose_bf16_kernel(
    const float* __restrict__ in, bf16* __restrict__ outp, int R, int C)
{
    int tilesR = R >> 6, tilesC = C >> 6;
    int per = tilesR * tilesC;
    int bx = blockIdx.x;
    int e  = bx / per; int r2 = bx % per;
    int tr = r2 / tilesC, tc = r2 % tilesC;
    int r0 = tr << 6, c0 = tc << 6;
    const float* ip = in  + (size_t)e * R * C;
    bf16*        op = outp + (size_t)e * R * C;

    __shared__ uint32_t T[64][36];   // [col][row-pair], padded stride
    int t = threadIdx.x;
    int rp = t >> 4;          // 0..15
    int c4 = (t & 15) * 4;

#pragma unroll
    for (int it = 0; it < 2; ++it) {
        int pr = rp + 16 * it;    // pair index 0..31
        const float* p = ip + (size_t)(r0 + 2*pr) * C + c0 + c4;
        float4 a = *(const float4*)(p);
        float4 b = *(const float4*)(p + C);
        T[c4+0][pr] = pack2(a.x, b.x);
        T[c4+1][pr] = pack2(a.y, b.y);
        T[c4+2][pr] = pack2(a.z, b.z);
        T[c4+3][pr] = pack2(a.w, b.w);
    }
    __syncthreads();

    int s     = t & 7;        // 16B segment within output row
    int cbase = t >> 3;       // 0..31
#pragma unroll
    for (int pass = 0; pass < 2; ++pass) {
        int cc = cbase + 32 * pass;
        uint4 u = *(const uint4*)&T[cc][4*s];
        *(uint4*)(op + (size_t)(c0 + cc) * R + r0 + 8*s) = u;
    }
}

// ---------------- gather tokens into compacted bf16 A-matrix ----------------
__global__ __launch_bounds__(256) void gather_kernel(
    const float* __restrict__ x, const int* __restrict__ cnt, const int* __restrict__ off,
    const int* __restrict__ tok_list, bf16* __restrict__ Xg)
{
    int bx = blockIdx.x;
    int e  = bx >> 12;
    int i  = bx & 4095;
    if (i >= cnt[e]) return;
    int tok = tok_list[e*NTOK + i];
    size_t row = (size_t)(off[e] + i);
    int t = threadIdx.x;
    float4 v = *(const float4*)(x + (size_t)tok * D_ + t*4);
    uint2 uu;
    uu.x = pack2(v.x, v.y);
    uu.y = pack2(v.z, v.w);
    *(uint2*)(Xg + row * D_ + t*4) = uu;
}

// ============ GEMM1: H = gelu(Xg @ W1 + b1), bf16 out ============
__global__ __launch_bounds__(256) void gemm1_kernel(
    const bf16* __restrict__ Xg, const bf16* __restrict__ W1t,
    const float* __restrict__ b1, const int* __restrict__ cnt,
    const int* __restrict__ off, bf16* __restrict__ H)
{
    int bx = blockIdx.x;
    int e  = bx >> 10;
    int r2 = bx & 1023;
    int mtile = r2 >> 5, ntile = r2 & 31;
    int n = cnt[e];
    if (mtile * 128 >= n) return;
    int row0 = off[e] + mtile * 128;
    int f0 = ntile * 128;

    __shared__ bf16 As[128*64];
    __shared__ bf16 Bs[128*64];

    int t = threadIdx.x;
    int wave = t >> 6, lane = t & 63;
    int wm = wave & 1, wn = wave >> 1;
    int q = lane >> 4, ln = lane & 15;
    int sm = lane >> 3, sc = lane & 7;

    const bf16* Abase = Xg  + (size_t)row0 * D_;
    const bf16* Bbase = W1t + ((size_t)e * F_ + f0) * D_;

    floatx4 acc[4][4];
#pragma unroll
    for (int mt = 0; mt < 4; ++mt)
#pragma unroll
        for (int nt = 0; nt < 4; ++nt) acc[mt][nt] = {0.f, 0.f, 0.f, 0.f};

    for (int kt = 0; kt < D_; kt += 64) {
        __syncthreads();
#pragma unroll
        for (int i = 0; i < 4; ++i) {
            int g = wave*4 + i;
            int m = g*8 + sm;
            int ca = sc ^ (m & 7);
            async_load16(Abase + (size_t)m * D_ + kt + ca*8, &As[g*512]);
            async_load16(Bbase + (size_t)m * D_ + kt + ca*8, &Bs[g*512]);
        }
        __syncthreads();
#pragma unroll
        for (int kk = 0; kk < 2; ++kk) {
            short8 av[4], bv[4];
#pragma unroll
            for (int mt = 0; mt < 4; ++mt) {
                int r = wm*64 + mt*16 + ln;
                int cs = (kk*4 + q) ^ (r & 7);
                av[mt] = *(const short8*)&As[r*64 + cs*8];
            }
#pragma unroll
            for (int nt = 0; nt < 4; ++nt) {
                int r = wn*64 + nt*16 + ln;
                int cs = (kk*4 + q) ^ (r & 7);
                bv[nt] = *(const short8*)&Bs[r*64 + cs*8];
            }
#pragma unroll
            for (int mt = 0; mt < 4; ++mt)
#pragma unroll
                for (int nt = 0; nt < 4; ++nt)
                    acc[mt][nt] = __builtin_amdgcn_mfma_f32_16x16x32_bf16(av[mt], bv[nt], acc[mt][nt], 0, 0, 0);
        }
    }

#pragma unroll
    for (int nt = 0; nt < 4; ++nt) {
        int f = f0 + wn*64 + nt*16 + ln;
        float b1v = b1[(size_t)e * F_ + f];
#pragma unroll
        for (int mt = 0; mt < 4; ++mt) {
            int rl = wm*64 + mt*16 + q*4;
#pragma unroll
            for (int r = 0; r < 4; ++r) {
                float v = acc[mt][nt][r] + b1v;
                H[(size_t)(row0 + rl + r) * F_ + f] = __float2bfloat16(fast_gelu(v));
            }
        }
    }
}

// ============ GEMM2: Y[row] = H @ W2 + b2 (bf16, plain stores; no atomics) ============
__global__ __launch_bounds__(256) void gemm2_kernel(
    const bf16* __restrict__ H, const bf16* __restrict__ W2t,
    const float* __restrict__ b2, const int* __restrict__ cnt, const int* __restrict__ off,
    bf16* __restrict__ Y)
{
    int bx = blockIdx.x;
    int e   = bx >> 8;           // 32 mtiles * 8 ntiles per expert
    int rem = bx & 255;
    int mtile = rem >> 3;
    int ntile = rem & 7;
    int n = cnt[e];
    if (mtile * 128 >= n) return;
    int row0 = off[e] + mtile * 128;
    int d0 = ntile * 128;

    __shared__ bf16 As[128*64];
    __shared__ bf16 Bs[128*64];

    int t = threadIdx.x;
    int wave = t >> 6, lane = t & 63;
    int wm = wave & 1, wn = wave >> 1;
    int q = lane >> 4, ln = lane & 15;
    int sm = lane >> 3, sc = lane & 7;

    const bf16* Abase = H   + (size_t)row0 * F_;
    const bf16* Bbase = W2t + ((size_t)e * D_ + d0) * F_;

    floatx4 acc[4][4];
#pragma unroll
    for (int mt = 0; mt < 4; ++mt)
#pragma unroll
        for (int nt = 0; nt < 4; ++nt) acc[mt][nt] = {0.f, 0.f, 0.f, 0.f};

    for (int kt = 0; kt < F_; kt += 64) {
        __syncthreads();
#pragma unroll
        for (int i = 0; i < 4; ++i) {
            int g = wave*4 + i;
            int m = g*8 + sm;
            int ca = sc ^ (m & 7);
            async_load16(Abase + (size_t)m * F_ + kt + ca*8, &As[g*512]);
            async_load16(Bbase + (size_t)m * F_ + kt + ca*8, &Bs[g*512]);
        }
        __syncthreads();
#pragma unroll
        for (int kk = 0; kk < 2; ++kk) {
            short8 av[4], bv[4];
#pragma unroll
            for (int mt = 0; mt < 4; ++mt) {
                int r = wm*64 + mt*16 + ln;
                int cs = (kk*4 + q) ^ (r & 7);
                av[mt] = *(const short8*)&As[r*64 + cs*8];
            }
#pragma unroll
            for (int nt = 0; nt < 4; ++nt) {
                int r = wn*64 + nt*16 + ln;
                int cs = (kk*4 + q) ^ (r & 7);
                bv[nt] = *(const short8*)&Bs[r*64 + cs*8];
            }
#pragma unroll
            for (int mt = 0; mt < 4; ++mt)
#pragma unroll
                for (int nt = 0; nt < 4; ++nt)
                    acc[mt][nt] = __builtin_amdgcn_mfma_f32_16x16x32_bf16(av[mt], bv[nt], acc[mt][nt], 0, 0, 0);
        }
    }

    float b2v[4];
#pragma unroll
    for (int nt = 0; nt < 4; ++nt)
        b2v[nt] = b2[(size_t)e * D_ + d0 + wn*64 + nt*16 + ln];

#pragma unroll
    for (int mt = 0; mt < 4; ++mt) {
#pragma unroll
        for (int r = 0; r < 4; ++r) {
            int loc = wm*64 + mt*16 + q*4 + r;
            int i = mtile*128 + loc;
            if (i < n) {
                bf16* yp = Y + (size_t)(row0 + loc) * D_ + d0;
#pragma unroll
                for (int nt = 0; nt < 4; ++nt)
                    yp[wn*64 + nt*16 + ln] = __float2bfloat16(acc[mt][nt][r] + b2v[nt]);
            }
        }
    }
}

// ---------------- combine: out[tok] = w0*Y[row0] + w1*Y[row1] ----------------
__global__ __launch_bounds__(256) void combine_kernel(
    const bf16* __restrict__ Y, const int* __restrict__ rowid,
    const float* __restrict__ top_w, const int* __restrict__ off,
    float* __restrict__ out)
{
    int tok = blockIdx.x;
    int t = threadIdx.x;
    int v0 = rowid[tok], v1 = rowid[NTOK + tok];
    float w0 = top_w[tok], w1 = top_w[NTOK + tok];
    size_t r0 = (size_t)(off[v0 >> 13] + (v0 & 8191));
    size_t r1 = (size_t)(off[v1 >> 13] + (v1 & 8191));
    uint2 a = *(const uint2*)(Y + r0 * D_ + t*4);
    uint2 b = *(const uint2*)(Y + r1 * D_ + t*4);
    float4 o;
    o.x = w0 * ublo(a.x) + w1 * ublo(b.x);
    o.y = w0 * ubhi(a.x) + w1 * ubhi(b.x);
    o.z = w0 * ublo(a.y) + w1 * ublo(b.y);
    o.w = w0 * ubhi(a.y) + w1 * ubhi(b.y);
    *(float4*)(out + (size_t)tok * D_ + t*4) = o;
}

extern "C" void kernel_launch(void* const* d_in, const int* in_sizes, int n_in,
                              void* d_out, int out_size, void* d_ws, size_t ws_size,
                              hipStream_t stream)
{
    const float* x  = (const float*)d_in[0];
    const float* Wg = (const float*)d_in[1];
    const float* bg = (const float*)d_in[2];
    const float* W1 = (const float*)d_in[3];
    const float* b1 = (const float*)d_in[4];
    const float* W2 = (const float*)d_in[5];
    const float* b2 = (const float*)d_in[6];
    float* out = (float*)d_out;

    char* ws = (char*)d_ws;
    int*      cnt      = (int*)(ws + 0);
    int*      off      = (int*)(ws + 128);
    float*    psum_pad = (float*)(ws + 1024);
    uint32_t* top_ids  = (uint32_t*)(ws + 8192);
    float*    top_w    = (float*)(ws + 8192 + 16384);
    int*      tok_list = (int*)(ws + 65536);
    float*    w_list   = (float*)(ws + 65536 + 131072);
    int*      rowid    = (int*)(ws + 327680);            // [2][NTOK]
    size_t o = 1u << 20;
    bf16*  W1t = (bf16*)(ws + o);  o += (size_t)E_ * D_ * F_ * 2;   // 64 MB
    bf16*  W2t = (bf16*)(ws + o);  o += (size_t)E_ * F_ * D_ * 2;   // 64 MB
    bf16*  Xg  = (bf16*)(ws + o);  o += (size_t)MAXROWS * D_ * 2;   // 18.9 MB
    bf16*  H   = (bf16*)(ws + o);                                    // 75.5 MB
    bf16*  Y   = Xg;   // alias: Xg dead after gemm1; Y written by gemm2 (same size/shape)

    hipMemsetAsync(ws + 1024, 0, 1024, stream);   // psum_pad

    transpose_bf16_kernel<<<E_ * 16 * 64, 256, 0, stream>>>(W1, W1t, D_, F_);  // -> [E][F][D]
    transpose_bf16_kernel<<<E_ * 64 * 16, 256, 0, stream>>>(W2, W2t, F_, D_);  // -> [E][D][F]

    gate_kernel<<<256, 256, 0, stream>>>(x, Wg, bg, psum_pad, top_ids, top_w);
    compact_kernel<<<E_, 256, 0, stream>>>(top_ids, top_w, cnt, tok_list, w_list, rowid);
    finalize_gate_kernel<<<1, 1, 0, stream>>>(cnt, psum_pad, off, out + (size_t)NTOK * D_);
    gather_kernel<<<E_ * 4096, 256, 0, stream>>>(x, cnt, off, tok_list, Xg);

    gemm1_kernel<<<E_ * 32 * 32, 256, 0, stream>>>(Xg, W1t, b1, cnt, off, H);
    gemm2_kernel<<<E_ * 32 * 8, 256, 0, stream>>>(H, W2t, b2, cnt, off, Y);
    combine_kernel<<<NTOK, 256, 0, stream>>>(Y, rowid, top_w, off, out);
}